// Round 1
// baseline (469.678 us; speedup 1.0000x reference)
//
#include <hip/hip_runtime.h>

#define N_NODES 50000
#define N_EDGES 800000
#define IN_DIM 128
#define HID 64

// ---------------- CSR build ----------------

__global__ void deg_kernel(const int* __restrict__ dst, int* __restrict__ deg, int nE) {
    int i = blockIdx.x * blockDim.x + threadIdx.x;
    if (i < nE) atomicAdd(&deg[dst[i]], 1);
}

// per-block exclusive scan of deg (chunks of 256), block totals to blksum
__global__ void scan1_kernel(const int* __restrict__ deg, int* __restrict__ row_ptr,
                             int* __restrict__ blksum, int n) {
    __shared__ int sh[256];
    int t = threadIdx.x;
    int i = blockIdx.x * 256 + t;
    int v = (i < n) ? deg[i] : 0;
    sh[t] = v;
    __syncthreads();
    for (int off = 1; off < 256; off <<= 1) {
        int add = (t >= off) ? sh[t - off] : 0;
        __syncthreads();
        sh[t] += add;
        __syncthreads();
    }
    int incl = sh[t];
    if (i < n) row_ptr[i] = incl - v;          // exclusive within block
    if (t == 255) blksum[blockIdx.x] = incl;   // block total
}

// serial exclusive scan of block sums (196 elements — trivial)
__global__ void scan2_kernel(int* __restrict__ blksum, int nblk) {
    if (blockIdx.x == 0 && threadIdx.x == 0) {
        int run = 0;
        for (int b = 0; b < nblk; b++) { int t = blksum[b]; blksum[b] = run; run += t; }
    }
}

// add block offsets, init cursor, cap row_ptr
__global__ void scan3_kernel(int* __restrict__ row_ptr, const int* __restrict__ blksum,
                             int* __restrict__ cursor, int n, int nE) {
    int i = blockIdx.x * 256 + threadIdx.x;
    if (i < n) {
        int r = row_ptr[i] + blksum[i >> 8];
        row_ptr[i] = r;
        cursor[i] = r;
    }
    if (i == 0) row_ptr[n] = nE;
}

__global__ void fill_kernel(const int* __restrict__ src, const int* __restrict__ dst,
                            int* __restrict__ cursor, int* __restrict__ col, int nE) {
    int i = blockIdx.x * blockDim.x + threadIdx.x;
    if (i < nE) {
        int p = atomicAdd(&cursor[dst[i]], 1);
        col[p] = src[i];
    }
}

// ---------------- fc_init: h0 = relu(features @ fc_w + fc_b) ----------------
// one wave per node; lane = output feature; fc_w (128x64, 32KB) staged in LDS

__global__ __launch_bounds__(256) void fc_init_kernel(
        const float* __restrict__ feat, const float* __restrict__ W,
        const float* __restrict__ bias, float* __restrict__ h, int n) {
    __shared__ float Wl[IN_DIM * HID];
    for (int i = threadIdx.x; i < IN_DIM * HID; i += 256) Wl[i] = W[i];
    __syncthreads();
    int wid = threadIdx.x >> 6, lane = threadIdx.x & 63;
    int node = blockIdx.x * 4 + wid;
    if (node >= n) return;

    float f0 = feat[node * IN_DIM + lane];
    float f1 = feat[node * IN_DIM + 64 + lane];
    float acc = bias[lane];
#pragma unroll
    for (int k = 0; k < 64; k++) acc = fmaf(__shfl(f0, k), Wl[k * HID + lane], acc);
#pragma unroll
    for (int k = 0; k < 64; k++) acc = fmaf(__shfl(f1, k), Wl[(64 + k) * HID + lane], acc);
    h[node * HID + lane] = fmaxf(acc, 0.f);
}

// ---------------- fused GIN layer ----------------
// one wave per node: gather-mean over CSR neighbors, rst=(1+eps)h+mean,
// out = relu(rst @ W + b) with W (64x64) in LDS, rst broadcast via shfl.

__global__ __launch_bounds__(256) void gin_layer_kernel(
        const float* __restrict__ h_in, const int* __restrict__ row_ptr,
        const int* __restrict__ col, const float* __restrict__ W,
        const float* __restrict__ bias, const float* __restrict__ eps_arr, int layer,
        float* __restrict__ h_out, int n) {
    __shared__ float Wl[HID * HID];
    for (int i = threadIdx.x; i < HID * HID; i += 256) Wl[i] = W[i];
    __syncthreads();
    int wid = threadIdx.x >> 6, lane = threadIdx.x & 63;
    int node = blockIdx.x * 4 + wid;
    if (node >= n) return;

    int s0 = row_ptr[node], s1 = row_ptr[node + 1];
    float acc = 0.f;
    for (int e0 = s0; e0 < s1; e0 += 64) {
        int cnt = s1 - e0; if (cnt > 64) cnt = 64;
        int myc = (lane < cnt) ? col[e0 + lane] : 0;
        for (int j = 0; j < cnt; j++) {
            int srcn = __shfl(myc, j);
            acc += h_in[srcn * HID + lane];
        }
    }
    int d = s1 - s0;
    float mean = acc / (float)(d > 0 ? d : 1);
    float eps = eps_arr[layer];
    float rst = (1.f + eps) * h_in[node * HID + lane] + mean;

    float o = bias[lane];
#pragma unroll
    for (int k = 0; k < 64; k++) o = fmaf(__shfl(rst, k), Wl[k * HID + lane], o);
    h_out[node * HID + lane] = fmaxf(o, 0.f);
}

// ---------------- launch ----------------

extern "C" void kernel_launch(void* const* d_in, const int* in_sizes, int n_in,
                              void* d_out, int out_size, void* d_ws, size_t ws_size,
                              hipStream_t stream) {
    const float* feat = (const float*)d_in[0];
    const int*   src  = (const int*)d_in[1];
    const int*   dst  = (const int*)d_in[2];
    const float* fc_w = (const float*)d_in[3];
    const float* fc_b = (const float*)d_in[4];
    const float* w0   = (const float*)d_in[5];
    const float* b0   = (const float*)d_in[6];
    const float* w1   = (const float*)d_in[7];
    const float* b1   = (const float*)d_in[8];
    const float* w2   = (const float*)d_in[9];
    const float* b2   = (const float*)d_in[10];
    const float* eps  = (const float*)d_in[11];
    float* out = (float*)d_out;

    // workspace layout (256B aligned regions)
    char* ws = (char*)d_ws;
    size_t off = 0;
    auto alloc = [&](size_t bytes) {
        size_t o = off;
        off += (bytes + 255) & ~(size_t)255;
        return (void*)(ws + o);
    };
    int*   deg     = (int*)alloc((size_t)N_NODES * 4);
    int*   row_ptr = (int*)alloc((size_t)(N_NODES + 1) * 4);
    int*   cursor  = (int*)alloc((size_t)N_NODES * 4);
    int*   blksum  = (int*)alloc(256 * 4);
    int*   col     = (int*)alloc((size_t)N_EDGES * 4);
    float* hA      = (float*)alloc((size_t)N_NODES * HID * 4);
    float* hB      = (float*)alloc((size_t)N_NODES * HID * 4);

    const int nblkN = (N_NODES + 255) / 256;   // 196
    const int nblkE = (N_EDGES + 255) / 256;   // 3125

    // CSR build
    hipMemsetAsync(deg, 0, (size_t)N_NODES * 4, stream);
    deg_kernel<<<nblkE, 256, 0, stream>>>(dst, deg, N_EDGES);
    scan1_kernel<<<nblkN, 256, 0, stream>>>(deg, row_ptr, blksum, N_NODES);
    scan2_kernel<<<1, 64, 0, stream>>>(blksum, nblkN);
    scan3_kernel<<<nblkN, 256, 0, stream>>>(row_ptr, blksum, cursor, N_NODES, N_EDGES);
    fill_kernel<<<nblkE, 256, 0, stream>>>(src, dst, cursor, col, N_EDGES);

    // fc_init + 3 fused GIN layers
    const int nodeBlocks = (N_NODES + 3) / 4;  // 12500 (4 waves/block, 1 node/wave)
    fc_init_kernel<<<nodeBlocks, 256, 0, stream>>>(feat, fc_w, fc_b, hA, N_NODES);
    gin_layer_kernel<<<nodeBlocks, 256, 0, stream>>>(hA, row_ptr, col, w0, b0, eps, 0, hB, N_NODES);
    gin_layer_kernel<<<nodeBlocks, 256, 0, stream>>>(hB, row_ptr, col, w1, b1, eps, 1, hA, N_NODES);
    gin_layer_kernel<<<nodeBlocks, 256, 0, stream>>>(hA, row_ptr, col, w2, b2, eps, 2, out, N_NODES);
}

// Round 2
// 371.965 us; speedup vs baseline: 1.2627x; 1.2627x over previous
//
#include <hip/hip_runtime.h>

#define N_NODES 50000
#define N_EDGES 800000
#define IN_DIM 128
#define HID 64
#define NT 64   // nodes per block in fused layer kernels

using v4f = __attribute__((ext_vector_type(4))) float;

// ---------------- CSR build ----------------

__global__ void deg_kernel(const int* __restrict__ dst, int* __restrict__ deg, int nE) {
    int i = blockIdx.x * blockDim.x + threadIdx.x;
    if (i < nE) atomicAdd(&deg[dst[i]], 1);
}

__global__ void scan1_kernel(const int* __restrict__ deg, int* __restrict__ row_ptr,
                             int* __restrict__ blksum, int n) {
    __shared__ int sh[256];
    int t = threadIdx.x;
    int i = blockIdx.x * 256 + t;
    int v = (i < n) ? deg[i] : 0;
    sh[t] = v;
    __syncthreads();
    for (int off = 1; off < 256; off <<= 1) {
        int add = (t >= off) ? sh[t - off] : 0;
        __syncthreads();
        sh[t] += add;
        __syncthreads();
    }
    int incl = sh[t];
    if (i < n) row_ptr[i] = incl - v;
    if (t == 255) blksum[blockIdx.x] = incl;
}

__global__ void scan2_kernel(int* __restrict__ blksum, int nblk) {
    if (blockIdx.x == 0 && threadIdx.x == 0) {
        int run = 0;
        for (int b = 0; b < nblk; b++) { int t = blksum[b]; blksum[b] = run; run += t; }
    }
}

__global__ void scan3_kernel(int* __restrict__ row_ptr, const int* __restrict__ blksum,
                             int* __restrict__ cursor, int n, int nE) {
    int i = blockIdx.x * 256 + threadIdx.x;
    if (i < n) {
        int r = row_ptr[i] + blksum[i >> 8];
        row_ptr[i] = r;
        cursor[i] = r;
    }
    if (i == 0) row_ptr[n] = nE;
}

__global__ void fill_kernel(const int* __restrict__ src, const int* __restrict__ dst,
                            int* __restrict__ cursor, int* __restrict__ col, int nE) {
    int i = blockIdx.x * blockDim.x + threadIdx.x;
    if (i < nE) {
        int p = atomicAdd(&cursor[dst[i]], 1);
        col[p] = src[i];
    }
}

// ---------------- fc_init: h0 = relu(features @ fc_w + fc_b) ----------------
// block = 256 thr, 64 nodes. feat tile + W staged in LDS; each thread computes
// a 4-node x 4-output register tile. Pitch 132 on feat tile: conflict-free
// broadcast reads (rows 4 apart -> 16 banks apart) and 16B-aligned f4 writes.

#define FT_PITCH 132

__global__ __launch_bounds__(256) void fc_init_kernel(
        const float* __restrict__ feat, const float* __restrict__ W,
        const float* __restrict__ bias, float* __restrict__ h, int n) {
    __shared__ float Wl[IN_DIM * HID];      // 32 KB, natural [k][o]
    __shared__ float ft[NT * FT_PITCH];     // 33 KB

    int base = blockIdx.x * NT;
    // stage W (coalesced f4)
    for (int i = threadIdx.x; i < IN_DIM * HID / 4; i += 256)
        *reinterpret_cast<v4f*>(&Wl[i * 4]) = *reinterpret_cast<const v4f*>(&W[i * 4]);
    // stage feat tile: 64 rows x 32 f4
    {
        int f4 = threadIdx.x & 31;
        int r0 = threadIdx.x >> 5;   // 0..7
        for (int p = 0; p < 8; ++p) {
            int r = p * 8 + r0;
            int node = base + r;
            v4f v = {0.f, 0.f, 0.f, 0.f};
            if (node < n) v = *reinterpret_cast<const v4f*>(&feat[(size_t)node * IN_DIM + f4 * 4]);
            *reinterpret_cast<v4f*>(&ft[r * FT_PITCH + f4 * 4]) = v;
        }
    }
    __syncthreads();

    int tx = threadIdx.x & 15;   // output quad: outputs tx*4..tx*4+3
    int ty = threadIdx.x >> 4;   // node quad: nodes ty*4..ty*4+3
    v4f acc[4];
    v4f b4 = *reinterpret_cast<const v4f*>(&bias[tx * 4]);
    acc[0] = b4; acc[1] = b4; acc[2] = b4; acc[3] = b4;

#pragma unroll 16
    for (int k = 0; k < IN_DIM; ++k) {
        v4f w4 = *reinterpret_cast<const v4f*>(&Wl[k * HID + tx * 4]);
        float a0 = ft[(ty * 4 + 0) * FT_PITCH + k];
        float a1 = ft[(ty * 4 + 1) * FT_PITCH + k];
        float a2 = ft[(ty * 4 + 2) * FT_PITCH + k];
        float a3 = ft[(ty * 4 + 3) * FT_PITCH + k];
        acc[0] += a0 * w4;
        acc[1] += a1 * w4;
        acc[2] += a2 * w4;
        acc[3] += a3 * w4;
    }
#pragma unroll
    for (int i = 0; i < 4; ++i) {
        int node = base + ty * 4 + i;
        if (node < n) {
            v4f o;
            o[0] = fmaxf(acc[i][0], 0.f);
            o[1] = fmaxf(acc[i][1], 0.f);
            o[2] = fmaxf(acc[i][2], 0.f);
            o[3] = fmaxf(acc[i][3], 0.f);
            *reinterpret_cast<v4f*>(&h[(size_t)node * HID + tx * 4]) = o;
        }
    }
}

// ---------------- fused GIN layer ----------------
// Phase A: wave-per-node gather-mean (coalesced 256B row loads), rst -> LDS.
// Phase B: 64x64x64 GEMM, 4x4 register tile per thread, W in LDS.

#define RST_PITCH 66   // rows 4 apart -> 8 banks apart: conflict-free broadcasts

__global__ __launch_bounds__(256) void gin_layer_kernel(
        const float* __restrict__ h_in, const int* __restrict__ row_ptr,
        const int* __restrict__ col, const float* __restrict__ W,
        const float* __restrict__ bias, const float* __restrict__ eps_arr, int layer,
        float* __restrict__ h_out, int n) {
    __shared__ float Wl[HID * HID];         // 16 KB
    __shared__ float rst[NT * RST_PITCH];   // 16.5 KB

    for (int i = threadIdx.x; i < HID * HID / 4; i += 256)
        *reinterpret_cast<v4f*>(&Wl[i * 4]) = *reinterpret_cast<const v4f*>(&W[i * 4]);

    int wid = threadIdx.x >> 6, lane = threadIdx.x & 63;
    int base = blockIdx.x * NT;
    float eps1 = 1.f + eps_arr[layer];

    // phase A: each wave gathers 16 nodes
    for (int t = 0; t < 16; ++t) {
        int r = wid * 16 + t;
        int node = base + r;
        if (node < n) {
            int s0 = row_ptr[node], s1 = row_ptr[node + 1];
            float acc0 = 0.f, acc1 = 0.f;
            for (int e0 = s0; e0 < s1; e0 += 64) {
                int cnt = s1 - e0; if (cnt > 64) cnt = 64;
                int myc = (lane < cnt) ? col[e0 + lane] : 0;
                int j = 0;
                for (; j + 1 < cnt; j += 2) {
                    int sa = __shfl(myc, j);
                    int sb = __shfl(myc, j + 1);
                    acc0 += h_in[(size_t)sa * HID + lane];
                    acc1 += h_in[(size_t)sb * HID + lane];
                }
                if (j < cnt) acc0 += h_in[(size_t)__shfl(myc, j) * HID + lane];
            }
            int d = s1 - s0;
            float mean = (acc0 + acc1) * (d > 0 ? 1.f / (float)d : 0.f);
            rst[r * RST_PITCH + lane] = eps1 * h_in[(size_t)node * HID + lane] + mean;
        }
    }
    __syncthreads();

    // phase B: out = relu(rst @ W + b)
    int tx = threadIdx.x & 15;
    int ty = threadIdx.x >> 4;
    v4f acc[4];
    v4f b4 = *reinterpret_cast<const v4f*>(&bias[tx * 4]);
    acc[0] = b4; acc[1] = b4; acc[2] = b4; acc[3] = b4;

#pragma unroll 16
    for (int k = 0; k < HID; ++k) {
        v4f w4 = *reinterpret_cast<const v4f*>(&Wl[k * HID + tx * 4]);
        float a0 = rst[(ty * 4 + 0) * RST_PITCH + k];
        float a1 = rst[(ty * 4 + 1) * RST_PITCH + k];
        float a2 = rst[(ty * 4 + 2) * RST_PITCH + k];
        float a3 = rst[(ty * 4 + 3) * RST_PITCH + k];
        acc[0] += a0 * w4;
        acc[1] += a1 * w4;
        acc[2] += a2 * w4;
        acc[3] += a3 * w4;
    }
#pragma unroll
    for (int i = 0; i < 4; ++i) {
        int node = base + ty * 4 + i;
        if (node < n) {
            v4f o;
            o[0] = fmaxf(acc[i][0], 0.f);
            o[1] = fmaxf(acc[i][1], 0.f);
            o[2] = fmaxf(acc[i][2], 0.f);
            o[3] = fmaxf(acc[i][3], 0.f);
            *reinterpret_cast<v4f*>(&h_out[(size_t)node * HID + tx * 4]) = o;
        }
    }
}

// ---------------- launch ----------------

extern "C" void kernel_launch(void* const* d_in, const int* in_sizes, int n_in,
                              void* d_out, int out_size, void* d_ws, size_t ws_size,
                              hipStream_t stream) {
    const float* feat = (const float*)d_in[0];
    const int*   src  = (const int*)d_in[1];
    const int*   dst  = (const int*)d_in[2];
    const float* fc_w = (const float*)d_in[3];
    const float* fc_b = (const float*)d_in[4];
    const float* w0   = (const float*)d_in[5];
    const float* b0   = (const float*)d_in[6];
    const float* w1   = (const float*)d_in[7];
    const float* b1   = (const float*)d_in[8];
    const float* w2   = (const float*)d_in[9];
    const float* b2   = (const float*)d_in[10];
    const float* eps  = (const float*)d_in[11];
    float* out = (float*)d_out;

    char* ws = (char*)d_ws;
    size_t off = 0;
    auto alloc = [&](size_t bytes) {
        size_t o = off;
        off += (bytes + 255) & ~(size_t)255;
        return (void*)(ws + o);
    };
    int*   deg     = (int*)alloc((size_t)N_NODES * 4);
    int*   row_ptr = (int*)alloc((size_t)(N_NODES + 1) * 4);
    int*   cursor  = (int*)alloc((size_t)N_NODES * 4);
    int*   blksum  = (int*)alloc(256 * 4);
    int*   col     = (int*)alloc((size_t)N_EDGES * 4);
    float* hA      = (float*)alloc((size_t)N_NODES * HID * 4);
    float* hB      = (float*)alloc((size_t)N_NODES * HID * 4);

    const int nblkN = (N_NODES + 255) / 256;   // 196
    const int nblkE = (N_EDGES + 255) / 256;   // 3125

    hipMemsetAsync(deg, 0, (size_t)N_NODES * 4, stream);
    deg_kernel<<<nblkE, 256, 0, stream>>>(dst, deg, N_EDGES);
    scan1_kernel<<<nblkN, 256, 0, stream>>>(deg, row_ptr, blksum, N_NODES);
    scan2_kernel<<<1, 64, 0, stream>>>(blksum, nblkN);
    scan3_kernel<<<nblkN, 256, 0, stream>>>(row_ptr, blksum, cursor, N_NODES, N_EDGES);
    fill_kernel<<<nblkE, 256, 0, stream>>>(src, dst, cursor, col, N_EDGES);

    const int nodeBlocks = (N_NODES + NT - 1) / NT;  // 782
    fc_init_kernel<<<nodeBlocks, 256, 0, stream>>>(feat, fc_w, fc_b, hA, N_NODES);
    gin_layer_kernel<<<nodeBlocks, 256, 0, stream>>>(hA, row_ptr, col, w0, b0, eps, 0, hB, N_NODES);
    gin_layer_kernel<<<nodeBlocks, 256, 0, stream>>>(hB, row_ptr, col, w1, b1, eps, 1, hA, N_NODES);
    gin_layer_kernel<<<nodeBlocks, 256, 0, stream>>>(hA, row_ptr, col, w2, b2, eps, 2, out, N_NODES);
}

// Round 4
// 231.132 us; speedup vs baseline: 2.0321x; 1.6093x over previous
//
#include <hip/hip_runtime.h>

#define N_NODES 50000
#define N_EDGES 800000
#define IN_DIM 128
#define HID 64
#define NT 64        // nodes per block in fused layer kernels
#define RST_PITCH 68 // 272B rows: 16B-aligned, conflict-free broadcasts

using v4f = __attribute__((ext_vector_type(4))) float;

// ---------------- CSR build ----------------

__global__ void deg_kernel(const int* __restrict__ dst, int* __restrict__ deg, int nE) {
    int i = (blockIdx.x * blockDim.x + threadIdx.x) * 4;
    if (i + 3 < nE) {
        int4 d4 = *reinterpret_cast<const int4*>(&dst[i]);
        atomicAdd(&deg[d4.x], 1);
        atomicAdd(&deg[d4.y], 1);
        atomicAdd(&deg[d4.z], 1);
        atomicAdd(&deg[d4.w], 1);
    } else {
        for (int k = i; k < nE; ++k) atomicAdd(&deg[dst[k]], 1);
    }
}

__global__ void scan1_kernel(const int* __restrict__ deg, int* __restrict__ row_ptr,
                             int* __restrict__ blksum, int n) {
    __shared__ int sh[256];
    int t = threadIdx.x;
    int i = blockIdx.x * 256 + t;
    int v = (i < n) ? deg[i] : 0;
    sh[t] = v;
    __syncthreads();
    for (int off = 1; off < 256; off <<= 1) {
        int add = (t >= off) ? sh[t - off] : 0;
        __syncthreads();
        sh[t] += add;
        __syncthreads();
    }
    int incl = sh[t];
    if (i < n) row_ptr[i] = incl - v;
    if (t == 255) blksum[blockIdx.x] = incl;
}

// parallel one-block exclusive scan of block sums (nblk <= 256)
__global__ void scan2_kernel(int* __restrict__ blksum, int nblk) {
    __shared__ int sh[256];
    int t = threadIdx.x;
    int v = (t < nblk) ? blksum[t] : 0;
    sh[t] = v;
    __syncthreads();
    for (int off = 1; off < 256; off <<= 1) {
        int add = (t >= off) ? sh[t - off] : 0;
        __syncthreads();
        sh[t] += add;
        __syncthreads();
    }
    if (t < nblk) blksum[t] = sh[t] - v;
}

__global__ void scan3_kernel(int* __restrict__ row_ptr, const int* __restrict__ blksum,
                             int* __restrict__ cursor, int n, int nE) {
    int i = blockIdx.x * 256 + threadIdx.x;
    if (i < n) {
        int r = row_ptr[i] + blksum[i >> 8];
        row_ptr[i] = r;
        cursor[i] = r;
    }
    if (i == 0) row_ptr[n] = nE;
}

__global__ void fill_kernel(const int* __restrict__ src, const int* __restrict__ dst,
                            int* __restrict__ cursor, int* __restrict__ col, int nE) {
    int i = (blockIdx.x * blockDim.x + threadIdx.x) * 4;
    if (i + 3 < nE) {
        int4 s4 = *reinterpret_cast<const int4*>(&src[i]);
        int4 d4 = *reinterpret_cast<const int4*>(&dst[i]);
        col[atomicAdd(&cursor[d4.x], 1)] = s4.x;
        col[atomicAdd(&cursor[d4.y], 1)] = s4.y;
        col[atomicAdd(&cursor[d4.z], 1)] = s4.z;
        col[atomicAdd(&cursor[d4.w], 1)] = s4.w;
    } else {
        for (int k = i; k < nE; ++k) col[atomicAdd(&cursor[dst[k]], 1)] = src[k];
    }
}

// zero row N of both h buffers (gather target for invalid tail edges)
__global__ void zero_rows_kernel(float* __restrict__ hA, float* __restrict__ hB) {
    int l = threadIdx.x;
    hA[(size_t)N_NODES * HID + l] = 0.f;
    hB[(size_t)N_NODES * HID + l] = 0.f;
}

// ---------------- fc_init: h0 = relu(features @ fc_w + fc_b) ----------------

#define FT_PITCH 132

__global__ __launch_bounds__(256) void fc_init_kernel(
        const float* __restrict__ feat, const float* __restrict__ W,
        const float* __restrict__ bias, float* __restrict__ h, int n) {
    __shared__ float Wl[IN_DIM * HID];      // 32 KB
    __shared__ float ft[NT * FT_PITCH];     // 33 KB

    int base = blockIdx.x * NT;
    for (int i = threadIdx.x; i < IN_DIM * HID / 4; i += 256)
        *reinterpret_cast<v4f*>(&Wl[i * 4]) = *reinterpret_cast<const v4f*>(&W[i * 4]);
    {
        int f4 = threadIdx.x & 31;
        int r0 = threadIdx.x >> 5;
        for (int p = 0; p < 8; ++p) {
            int r = p * 8 + r0;
            int node = base + r;
            v4f v = {0.f, 0.f, 0.f, 0.f};
            if (node < n) v = *reinterpret_cast<const v4f*>(&feat[(size_t)node * IN_DIM + f4 * 4]);
            *reinterpret_cast<v4f*>(&ft[r * FT_PITCH + f4 * 4]) = v;
        }
    }
    __syncthreads();

    int tx = threadIdx.x & 15;
    int ty = threadIdx.x >> 4;
    v4f acc[4];
    v4f b4 = *reinterpret_cast<const v4f*>(&bias[tx * 4]);
    acc[0] = b4; acc[1] = b4; acc[2] = b4; acc[3] = b4;

#pragma unroll 16
    for (int k = 0; k < IN_DIM; ++k) {
        v4f w4 = *reinterpret_cast<const v4f*>(&Wl[k * HID + tx * 4]);
        float a0 = ft[(ty * 4 + 0) * FT_PITCH + k];
        float a1 = ft[(ty * 4 + 1) * FT_PITCH + k];
        float a2 = ft[(ty * 4 + 2) * FT_PITCH + k];
        float a3 = ft[(ty * 4 + 3) * FT_PITCH + k];
        acc[0] += a0 * w4;
        acc[1] += a1 * w4;
        acc[2] += a2 * w4;
        acc[3] += a3 * w4;
    }
#pragma unroll
    for (int i = 0; i < 4; ++i) {
        int node = base + ty * 4 + i;
        if (node < n) {
            v4f o;
            o[0] = fmaxf(acc[i][0], 0.f);
            o[1] = fmaxf(acc[i][1], 0.f);
            o[2] = fmaxf(acc[i][2], 0.f);
            o[3] = fmaxf(acc[i][3], 0.f);
            *reinterpret_cast<v4f*>(&h[(size_t)node * HID + tx * 4]) = o;
        }
    }
}

// ---------------- fused GIN layer (512 threads) ----------------
// Phase A: 8 waves x 8 nodes; 4 edges per load instruction (lane group g
// owns edge j*4+g, feature quad (lane&15)*4). Tail lanes carry index n
// (zero row), so the __shfl is UNCONDITIONAL -> convergent -> all source
// lanes active (divergent shfl reads 0 from inactive lanes: round-3 bug).
// Phase B: 64x64x64 GEMM, 2 nodes x 4 outputs per thread, W in LDS.

__global__ __launch_bounds__(512) void gin_layer_kernel(
        const float* __restrict__ h_in, const int* __restrict__ row_ptr,
        const int* __restrict__ col, const float* __restrict__ W,
        const float* __restrict__ bias, const float* __restrict__ eps_arr, int layer,
        float* __restrict__ h_out, int n) {
    __shared__ float Wl[HID * HID];         // 16 KB
    __shared__ float rst[NT * RST_PITCH];   // 17 KB

    for (int i = threadIdx.x; i < HID * HID / 4; i += 512)
        *reinterpret_cast<v4f*>(&Wl[i * 4]) = *reinterpret_cast<const v4f*>(&W[i * 4]);

    int wid = threadIdx.x >> 6, lane = threadIdx.x & 63;
    int g = lane >> 4;          // edge subgroup 0..3
    int fo = (lane & 15) * 4;   // feature quad offset
    int base = blockIdx.x * NT;
    float eps1 = 1.f + eps_arr[layer];

    // phase A: gather-mean, 8 nodes per wave
    for (int t = 0; t < 8; ++t) {
        int r = wid * 8 + t;
        int node = base + r;
        if (node < n) {
            int s0 = row_ptr[node], s1 = row_ptr[node + 1];
            v4f acc = {0.f, 0.f, 0.f, 0.f};
            for (int e0 = s0; e0 < s1; e0 += 64) {
                int cnt = s1 - e0; if (cnt > 64) cnt = 64;
                int myc = (lane < cnt) ? col[e0 + lane] : n;  // tail -> zero row
                int jmax = (cnt + 3) >> 2;
#pragma unroll 4
                for (int j = 0; j < jmax; ++j) {
                    int idx = j * 4 + g;                      // <= 63 always
                    int sn = __shfl(myc, idx);                // convergent
                    acc += *reinterpret_cast<const v4f*>(&h_in[(size_t)sn * HID + fo]);
                }
            }
#pragma unroll
            for (int c = 0; c < 4; ++c) acc[c] += __shfl_xor(acc[c], 16);
#pragma unroll
            for (int c = 0; c < 4; ++c) acc[c] += __shfl_xor(acc[c], 32);
            int d = s1 - s0;
            float sc = (d > 0) ? 1.f / (float)d : 0.f;
            if (lane < 16) {
                v4f self = *reinterpret_cast<const v4f*>(&h_in[(size_t)node * HID + fo]);
                v4f rv = eps1 * self + acc * sc;
                *reinterpret_cast<v4f*>(&rst[r * RST_PITCH + fo]) = rv;
            }
        }
    }
    __syncthreads();

    // phase B: out = relu(rst @ W + b)
    int tx = threadIdx.x & 15;   // output quad
    int ty = threadIdx.x >> 4;   // node pair 0..31
    v4f b4 = *reinterpret_cast<const v4f*>(&bias[tx * 4]);
    v4f acc0 = b4, acc1 = b4;

#pragma unroll 16
    for (int k = 0; k < HID; ++k) {
        v4f w4 = *reinterpret_cast<const v4f*>(&Wl[k * HID + tx * 4]);
        float a0 = rst[(ty * 2 + 0) * RST_PITCH + k];
        float a1 = rst[(ty * 2 + 1) * RST_PITCH + k];
        acc0 += a0 * w4;
        acc1 += a1 * w4;
    }
    {
        int node = base + ty * 2;
        if (node < n) {
            v4f o;
            o[0] = fmaxf(acc0[0], 0.f); o[1] = fmaxf(acc0[1], 0.f);
            o[2] = fmaxf(acc0[2], 0.f); o[3] = fmaxf(acc0[3], 0.f);
            *reinterpret_cast<v4f*>(&h_out[(size_t)node * HID + tx * 4]) = o;
        }
        node = base + ty * 2 + 1;
        if (node < n) {
            v4f o;
            o[0] = fmaxf(acc1[0], 0.f); o[1] = fmaxf(acc1[1], 0.f);
            o[2] = fmaxf(acc1[2], 0.f); o[3] = fmaxf(acc1[3], 0.f);
            *reinterpret_cast<v4f*>(&h_out[(size_t)node * HID + tx * 4]) = o;
        }
    }
}

// ---------------- launch ----------------

extern "C" void kernel_launch(void* const* d_in, const int* in_sizes, int n_in,
                              void* d_out, int out_size, void* d_ws, size_t ws_size,
                              hipStream_t stream) {
    const float* feat = (const float*)d_in[0];
    const int*   src  = (const int*)d_in[1];
    const int*   dst  = (const int*)d_in[2];
    const float* fc_w = (const float*)d_in[3];
    const float* fc_b = (const float*)d_in[4];
    const float* w0   = (const float*)d_in[5];
    const float* b0   = (const float*)d_in[6];
    const float* w1   = (const float*)d_in[7];
    const float* b1   = (const float*)d_in[8];
    const float* w2   = (const float*)d_in[9];
    const float* b2   = (const float*)d_in[10];
    const float* eps  = (const float*)d_in[11];
    float* out = (float*)d_out;

    char* ws = (char*)d_ws;
    size_t off = 0;
    auto alloc = [&](size_t bytes) {
        size_t o = off;
        off += (bytes + 255) & ~(size_t)255;
        return (void*)(ws + o);
    };
    int*   deg     = (int*)alloc((size_t)N_NODES * 4);
    int*   row_ptr = (int*)alloc((size_t)(N_NODES + 1) * 4);
    int*   cursor  = (int*)alloc((size_t)N_NODES * 4);
    int*   blksum  = (int*)alloc(256 * 4);
    int*   col     = (int*)alloc((size_t)N_EDGES * 4);
    float* hA      = (float*)alloc((size_t)(N_NODES + 1) * HID * 4);
    float* hB      = (float*)alloc((size_t)(N_NODES + 1) * HID * 4);

    const int nblkN = (N_NODES + 255) / 256;         // 196
    const int nblkE4 = (N_EDGES / 4 + 255) / 256;    // 782

    hipMemsetAsync(deg, 0, (size_t)N_NODES * 4, stream);
    zero_rows_kernel<<<1, 64, 0, stream>>>(hA, hB);
    deg_kernel<<<nblkE4, 256, 0, stream>>>(dst, deg, N_EDGES);
    scan1_kernel<<<nblkN, 256, 0, stream>>>(deg, row_ptr, blksum, N_NODES);
    scan2_kernel<<<1, 256, 0, stream>>>(blksum, nblkN);
    scan3_kernel<<<nblkN, 256, 0, stream>>>(row_ptr, blksum, cursor, N_NODES, N_EDGES);
    fill_kernel<<<nblkE4, 256, 0, stream>>>(src, dst, cursor, col, N_EDGES);

    const int nodeBlocks = (N_NODES + NT - 1) / NT;  // 782
    fc_init_kernel<<<nodeBlocks, 256, 0, stream>>>(feat, fc_w, fc_b, hA, N_NODES);
    gin_layer_kernel<<<nodeBlocks, 512, 0, stream>>>(hA, row_ptr, col, w0, b0, eps, 0, hB, N_NODES);
    gin_layer_kernel<<<nodeBlocks, 512, 0, stream>>>(hB, row_ptr, col, w1, b1, eps, 1, hA, N_NODES);
    gin_layer_kernel<<<nodeBlocks, 512, 0, stream>>>(hA, row_ptr, col, w2, b2, eps, 2, out, N_NODES);
}